// Round 1
// baseline (1820.559 us; speedup 1.0000x reference)
//
#include <hip/hip_runtime.h>
#include <hip/hip_fp16.h>
#include <stdint.h>

// Problem constants: B=8, H=W=128, C=F=256, K=7, PAD=3, rs=128
typedef _Float16 half8 __attribute__((ext_vector_type(8)));   // 8 fp16 = 4 VGPR (MFMA A/B frag)
typedef _Float16 half2v __attribute__((ext_vector_type(2)));  // packed fp16 pair
typedef __attribute__((ext_vector_type(4))) float f32x4;      // MFMA C/D frag

__device__ __forceinline__ unsigned short f2h(float f) {      // RNE fp32->fp16
  __half h = __float2half(f);
  unsigned short u; __builtin_memcpy(&u, &h, 2); return u;
}
__device__ __forceinline__ unsigned pk2h(float a, float b) {  // RTZ packed pair (staging only)
  auto v = __builtin_amdgcn_cvt_pkrtz(a, b);
  unsigned u; __builtin_memcpy(&u, &v, 4); return u;
}
__device__ __forceinline__ half2v h2cast(unsigned u) {
  half2v v; __builtin_memcpy(&v, &u, 4); return v;
}

#if __has_builtin(__builtin_amdgcn_fdot2)
__device__ __forceinline__ float dot2(half2v a, half2v b, float c) {
  return __builtin_amdgcn_fdot2(a, b, c, false);
}
#else
__device__ __forceinline__ float dot2(half2v a, half2v b, float c) {
  return c + (float)a[0] * (float)b[0] + (float)a[1] * (float)b[1];
}
#endif

// async global->LDS, 16B per lane; lds dest = wave-uniform base + lane*16
__device__ __forceinline__ void gl_lds16(const void* g, void* l) {
  __builtin_amdgcn_global_load_lds(
      (const __attribute__((address_space(1))) void*)g,
      (__attribute__((address_space(3))) void*)l, 16, 0, 0);
}

// ---------------- Kernel 0: x fp32 -> fp16 (into d_out scratch region) ----------------
__global__ __launch_bounds__(256) void xcvt(const float* __restrict__ x,
                                            unsigned short* __restrict__ xh) {
  const size_t i = ((size_t)blockIdx.x * 256 + threadIdx.x) * 8;
  float4 a = *(const float4*)&x[i];
  float4 b = *(const float4*)&x[i + 4];
  uint4 o;
  o.x = pk2h(a.x, a.y); o.y = pk2h(a.z, a.w);
  o.z = pk2h(b.x, b.y); o.w = pk2h(b.z, b.w);
  *(uint4*)&xh[i] = o;
}

// ---------------- Kernel 1: weight transpose + fp32->fp16 ----------------
__global__ __launch_bounds__(256) void wconv(const float* __restrict__ Wq,
                                             const float* __restrict__ Wk,
                                             const float* __restrict__ Wv,
                                             unsigned short* __restrict__ Wb) {
  const int e = blockIdx.x;
  const int w = e >> 8;
  const int n = e & 255;
  const float* W = (w == 0) ? Wq : ((w == 1) ? Wk : Wv);
  const int k = threadIdx.x;
  Wb[(size_t)e * 256 + k] = f2h(W[(size_t)k * 256 + n]);
}

// ---------------- Kernel 2: fused QKV GEMM (fp16 MFMA, global_load_lds staging) ----------
__global__ __launch_bounds__(256) void qkv_gemm(const unsigned short* __restrict__ xh,
                                                const unsigned short* __restrict__ Wb,
                                                unsigned short* __restrict__ qkv) {
  __shared__ unsigned char ldsb[32768];

  const int tid = threadIdx.x;
  const int l = tid & 63, l15 = l & 15, l4 = l >> 4;
  const int wv = tid >> 6, wr = wv >> 1, wc = wv & 1;

  // XCD-aware chunked swizzle: 6144 blocks, 8 XCDs, 768 per XCD (bijective).
  const int pid = blockIdx.x;
  const int cid = (pid & 7) * 768 + (pid >> 3);
  const int by = cid / 6;
  const int bx = cid - by * 6;
  const size_t row0 = (size_t)by * 128;
  const int n0 = bx * 128;

  const int rbase0 = wv * 32, rbase1 = wv * 32 + 16;
  const int rA0 = rbase0 + (l >> 2), rA1 = rbase1 + (l >> 2);
  const int q0 = (l & 3) ^ ((rA0 >> 1) & 3), q1 = (l & 3) ^ ((rA1 >> 1) & 3);
  const unsigned short* gA0 = xh + (row0 + rA0) * 256 + q0 * 8;
  const unsigned short* gA1 = xh + (row0 + rA1) * 256 + q1 * 8;
  const unsigned short* gB0 = Wb + (size_t)(n0 + rA0) * 256 + q0 * 8;
  const unsigned short* gB1 = Wb + (size_t)(n0 + rA1) * 256 + q1 * 8;

  f32x4 acc[4][4] = {};

  auto stage = [&](int s, int d) {
    gl_lds16(gA0 + s * 32, &ldsb[d * 8192 + rbase0 * 64]);
    gl_lds16(gA1 + s * 32, &ldsb[d * 8192 + rbase1 * 64]);
    gl_lds16(gB0 + s * 32, &ldsb[16384 + d * 8192 + rbase0 * 64]);
    gl_lds16(gB1 + s * 32, &ldsb[16384 + d * 8192 + rbase1 * 64]);
  };

  stage(0, 0);
  __syncthreads();

  for (int s = 0; s < 8; ++s) {
    const int d = s & 1;
    if (s < 7) stage(s + 1, d ^ 1);
    half8 af[4], bf[4];
#pragma unroll
    for (int m = 0; m < 4; ++m) {
      const int r = wr * 64 + m * 16 + l15;
      af[m] = *(const half8*)&ldsb[d * 8192 + r * 64 + ((l4 ^ ((r >> 1) & 3)) * 16)];
    }
#pragma unroll
    for (int n = 0; n < 4; ++n) {
      const int r = wc * 64 + n * 16 + l15;
      bf[n] = *(const half8*)&ldsb[16384 + d * 8192 + r * 64 + ((l4 ^ ((r >> 1) & 3)) * 16)];
    }
#pragma unroll
    for (int n = 0; n < 4; ++n)
#pragma unroll
      for (int m = 0; m < 4; ++m)
        acc[m][n] = __builtin_amdgcn_mfma_f32_16x16x32_f16(af[m], bf[n], acc[m][n], 0, 0, 0);
    __syncthreads();
  }

  // Epilogue: C/D mapping col=lane&15, row=(lane>>4)*4+reg (m89-verified)
#pragma unroll
  for (int m = 0; m < 4; ++m)
#pragma unroll
    for (int n = 0; n < 4; ++n) {
      const int ng = n0 + wc * 64 + n * 16 + l15;
      unsigned short* op = qkv + (size_t)(ng >> 8) * 33554432 + (ng & 255);
#pragma unroll
      for (int r = 0; r < 4; ++r) {
        const size_t grow = row0 + wr * 64 + m * 16 + l4 * 4 + r;
        op[grow * 256] = f2h(acc[m][n][r]);
      }
    }
}

// ---------------- Kernel 2b: per-pixel relative-position projections ----------------
__global__ __launch_bounds__(256) void qrel(const unsigned short* __restrict__ q,
                                            const float* __restrict__ relx,
                                            const float* __restrict__ rely,
                                            unsigned short* __restrict__ qr) {
  __shared__ unsigned wpk[896];  // [0..447] x-pairs, [448..895] y-pairs; wpk[c2*7+j]
  for (int i = threadIdx.x; i < 896; i += 256) {
    const int hf = (i >= 448) ? 1 : 0;
    const int r = i - hf * 448;
    const int c2 = r / 7, j = r - c2 * 7;
    const float* R = hf ? rely : relx;
    wpk[i] = pk2h(R[(2 * c2) * 7 + j], R[(2 * c2 + 1) * 7 + j]);
  }
  __syncthreads();
  const size_t pix = (size_t)blockIdx.x * 256 + threadIdx.x;
  const uint4* qp = (const uint4*)(q + pix * 256);  // 32 uint4 = 256 fp16 channels
  float ax[7] = {0, 0, 0, 0, 0, 0, 0}, ay[7] = {0, 0, 0, 0, 0, 0, 0};
#pragma unroll
  for (int g = 0; g < 32; ++g) {
    const uint4 u = qp[g];
    const int c2b = (g & 15) * 4;
    if (g < 16) {
#pragma unroll
      for (int j = 0; j < 7; ++j) {
        float s = ax[j];
        s = dot2(h2cast(u.x), h2cast(wpk[(c2b + 0) * 7 + j]), s);
        s = dot2(h2cast(u.y), h2cast(wpk[(c2b + 1) * 7 + j]), s);
        s = dot2(h2cast(u.z), h2cast(wpk[(c2b + 2) * 7 + j]), s);
        s = dot2(h2cast(u.w), h2cast(wpk[(c2b + 3) * 7 + j]), s);
        ax[j] = s;
      }
    } else {
#pragma unroll
      for (int j = 0; j < 7; ++j) {
        float s = ay[j];
        s = dot2(h2cast(u.x), h2cast(wpk[448 + (c2b + 0) * 7 + j]), s);
        s = dot2(h2cast(u.y), h2cast(wpk[448 + (c2b + 1) * 7 + j]), s);
        s = dot2(h2cast(u.z), h2cast(wpk[448 + (c2b + 2) * 7 + j]), s);
        s = dot2(h2cast(u.w), h2cast(wpk[448 + (c2b + 3) * 7 + j]), s);
        ay[j] = s;
      }
    }
  }
  uint4 o0, o1;
  o0.x = pk2h(ax[0], ax[1]); o0.y = pk2h(ax[2], ax[3]);
  o0.z = pk2h(ax[4], ax[5]); o0.w = pk2h(ax[6], ay[0]);
  o1.x = pk2h(ay[1], ay[2]); o1.y = pk2h(ay[3], ay[4]);
  o1.z = pk2h(ay[5], ay[6]); o1.w = 0;
  uint4* dst = (uint4*)(qr + pix * 512);
  dst[0] = o0; dst[1] = o1;
}

// ---------------- Kernel 3: fused windowed attention ----------------
// v2: latency-hiding restructure. rocprof showed the r6 synchronous pipeline is
// latency/barrier-bound (HBM 9%, VALU 31%, MfmaUtil 0, conflicts 0, occ 21% = structural
// 8 waves/CU): 32 barrier pairs exposed full global-load latency per chunk.
// Changes:
//  * 16x16 tile (halo 22x22 = 484 px, redundancy 1.89x vs 2.08x). Critically this lets a
//    DOUBLE-BUFFERED chunk fit 2 blocks/CU: 2 x 484*80 B = 77.4 KB/block, 155 KB/CU.
//  * Register-staged async prefetch: issue next chunk's global loads into statically-named
//    regs BEFORE the 49-tap compute, commit regs->other LDS buffer after. One barrier per
//    chunk (17 vs 33). Static indices only (r8 lesson: dynamic-index staging -> scratch).
//  * q prefetched one chunk ahead the same way.
//  * s_setprio(1) around dot clusters (T5: helps phase-split attn structures).
// LDS stride stays 40 shorts (80 B/px) -> measured-0-conflict b128 pattern unchanged.
__global__ __launch_bounds__(256) void attn(const unsigned short* __restrict__ qkv,
                                            const float* __restrict__ bias,
                                            const unsigned short* __restrict__ qrelb,
                                            float* __restrict__ out) {
  __shared__ unsigned short kv[2][484 * 40];  // 2 x 38720 B = 77440 B

  const int tid = threadIdx.x;
  const int col = tid & 15, row = tid >> 4;

  const int pid = blockIdx.x;
  const int cid = (pid & 7) * 64 + (pid >> 3);   // XCD-chunked (512 = 8*64, bijective)
  const int wt = cid & 7, ht = (cid >> 3) & 7, b = cid >> 6;

  const int h = ht * 16 + row, w = wt * 16 + col;
  const size_t pix = (size_t)((b * 128 + h) * 128 + w);
  const int pbase = (row * 22 + col) * 40;

  const unsigned short* qb = qkv;
  const unsigned short* kb = qkv + 33554432;
  const unsigned short* vb = qkv + 67108864;

  // halo staging geometry: thread covers halo px tid and tid+256 (if <484)
  const int p0 = tid;
  const int pr0 = p0 / 22, pc0 = p0 - pr0 * 22;
  const int gh0 = ht * 16 + pr0 - 3, gw0 = wt * 16 + pc0 - 3;
  const bool ok0 = ((unsigned)gh0 < 128u) && ((unsigned)gw0 < 128u);
  const long long go0 = ((long long)((b * 128 + gh0) * 128 + gw0)) * 256;  // in shorts
  const int d0 = p0 * 40;

  const int p1 = tid + 256;
  const bool act1 = (p1 < 484);
  const int pr1 = p1 / 22, pc1 = p1 - pr1 * 22;
  const int gh1 = ht * 16 + pr1 - 3, gw1 = wt * 16 + pc1 - 3;
  const bool ok1 = act1 && ((unsigned)gh1 < 128u) && ((unsigned)gw1 < 128u);
  const long long go1 = ((long long)((b * 128 + gh1) * 128 + gw1)) * 256;
  const int d1 = p1 * 40;

  // issue: global -> named regs (exec-masked, zeros for OOB halo)
  auto issue = [&](const unsigned short* base, int f0, uint4* st) {
    const uint4 z = make_uint4(0u, 0u, 0u, 0u);
    st[0] = z; st[1] = z; st[2] = z; st[3] = z;
    st[4] = z; st[5] = z; st[6] = z; st[7] = z;
    if (ok0) {
      const uint4* s = (const uint4*)(base + go0 + f0);
      st[0] = s[0]; st[1] = s[1]; st[2] = s[2]; st[3] = s[3];
    }
    if (ok1) {
      const uint4* s = (const uint4*)(base + go1 + f0);
      st[4] = s[0]; st[5] = s[1]; st[6] = s[2]; st[7] = s[3];
    }
  };
  // commit: regs -> LDS buffer (compiler inserts the vmcnt wait here, after compute)
  auto commit = [&](unsigned short* dst, const uint4* st) {
    uint4* d = (uint4*)&dst[d0];
    d[0] = st[0]; d[1] = st[1]; d[2] = st[2]; d[3] = st[3];
    if (act1) {
      uint4* e = (uint4*)&dst[d1];
      e[0] = st[4]; e[1] = st[5]; e[2] = st[6]; e[3] = st[7];
    }
  };

  // qrel: 14 fp16 at this pixel's out-slot head (written by qrel; we overwrite later)
  float qx[7], qy[7];
  {
    const uint4* rp = (const uint4*)(qrelb + pix * 512);
    uint4 r0 = rp[0], r1 = rp[1];
    half2v a0 = h2cast(r0.x), a1 = h2cast(r0.y), a2 = h2cast(r0.z), a3 = h2cast(r0.w);
    half2v b0 = h2cast(r1.x), b1 = h2cast(r1.y), b2 = h2cast(r1.z);
    qx[0] = a0[0]; qx[1] = a0[1]; qx[2] = a1[0]; qx[3] = a1[1];
    qx[4] = a2[0]; qx[5] = a2[1]; qx[6] = a3[0];
    qy[0] = a3[1]; qy[1] = b0[0]; qy[2] = b0[1]; qy[3] = b1[0];
    qy[4] = b1[1]; qy[5] = b2[0]; qy[6] = b2[1];
  }

  // prologue: stage K chunk 0 + load q chunk 0
  uint4 st[8];
  uint4 qc[4];
  issue(kb, 0, st);
  {
    const uint4* qs = (const uint4*)(qb + pix * 256);
    qc[0] = qs[0]; qc[1] = qs[1]; qc[2] = qs[2]; qc[3] = qs[3];
  }
  commit(kv[0], st);
  __syncthreads();

  float sc[49];
#pragma unroll
  for (int t = 0; t < 49; ++t) sc[t] = 0.0f;

  // ---- Phase A: scores (double-buffered; one barrier per chunk) ----
  for (int s = 0; s < 8; ++s) {
    const unsigned short* curb = kv[s & 1];
    unsigned short* nxtb = kv[(s & 1) ^ 1];
    // issue next chunk's loads NOW; latency hides under the 49-tap compute below
    if (s < 7) issue(kb, (s + 1) * 32, st);
    else       issue(vb, 0, st);            // phase B chunk 0
    uint4 qn[4];
    if (s < 7) {
      const uint4* qs = (const uint4*)(qb + pix * 256 + (s + 1) * 32);
      qn[0] = qs[0]; qn[1] = qs[1]; qn[2] = qs[2]; qn[3] = qs[3];
    }
    half2v qh[16];
    qh[0] = h2cast(qc[0].x); qh[1] = h2cast(qc[0].y); qh[2] = h2cast(qc[0].z); qh[3] = h2cast(qc[0].w);
    qh[4] = h2cast(qc[1].x); qh[5] = h2cast(qc[1].y); qh[6] = h2cast(qc[1].z); qh[7] = h2cast(qc[1].w);
    qh[8] = h2cast(qc[2].x); qh[9] = h2cast(qc[2].y); qh[10] = h2cast(qc[2].z); qh[11] = h2cast(qc[2].w);
    qh[12] = h2cast(qc[3].x); qh[13] = h2cast(qc[3].y); qh[14] = h2cast(qc[3].z); qh[15] = h2cast(qc[3].w);
    __builtin_amdgcn_s_setprio(1);
#pragma unroll
    for (int i = 0; i < 7; ++i)
#pragma unroll
      for (int j = 0; j < 7; ++j) {
        const uint4* kp = (const uint4*)&curb[pbase + (i * 22 + j) * 40];
        uint4 k0 = kp[0], k1 = kp[1], k2 = kp[2], k3 = kp[3];
        float s2 = sc[i * 7 + j];
        s2 = dot2(h2cast(k0.x), qh[0], s2);  s2 = dot2(h2cast(k0.y), qh[1], s2);
        s2 = dot2(h2cast(k0.z), qh[2], s2);  s2 = dot2(h2cast(k0.w), qh[3], s2);
        s2 = dot2(h2cast(k1.x), qh[4], s2);  s2 = dot2(h2cast(k1.y), qh[5], s2);
        s2 = dot2(h2cast(k1.z), qh[6], s2);  s2 = dot2(h2cast(k1.w), qh[7], s2);
        s2 = dot2(h2cast(k2.x), qh[8], s2);  s2 = dot2(h2cast(k2.y), qh[9], s2);
        s2 = dot2(h2cast(k2.z), qh[10], s2); s2 = dot2(h2cast(k2.w), qh[11], s2);
        s2 = dot2(h2cast(k3.x), qh[12], s2); s2 = dot2(h2cast(k3.y), qh[13], s2);
        s2 = dot2(h2cast(k3.z), qh[14], s2); s2 = dot2(h2cast(k3.w), qh[15], s2);
        sc[i * 7 + j] = s2;
      }
    __builtin_amdgcn_s_setprio(0);
    if (s < 7) { qc[0] = qn[0]; qc[1] = qn[1]; qc[2] = qn[2]; qc[3] = qn[3]; }
    commit(nxtb, st);    // vmcnt wait lands here, after ~2500 cyc of compute
    __syncthreads();
  }

  // ---- softmax over 49 (fp32, per thread); V chunk 0 already staged ----
#pragma unroll
  for (int i = 0; i < 7; ++i)
#pragma unroll
    for (int j = 0; j < 7; ++j) sc[i * 7 + j] += qx[j] + qy[i];
  float mx = sc[0];
#pragma unroll
  for (int t = 1; t < 49; ++t) mx = fmaxf(mx, sc[t]);
  float sum = 0.0f;
#pragma unroll
  for (int t = 0; t < 49; ++t) {
    float e = __expf(sc[t] - mx);
    sc[t] = e;
    sum += e;
  }
  const float invs = 1.0f / sum;
  unsigned pw[49];
#pragma unroll
  for (int t = 0; t < 49; ++t) {
    const unsigned short ph = f2h(sc[t] * invs);
    pw[t] = (unsigned)ph | ((unsigned)ph << 16);
  }

  // ---- Phase B: out = sum p*v + bias (same pipeline; parity continues at kv[0]) ----
  for (int s = 0; s < 8; ++s) {
    const unsigned short* curb = kv[s & 1];
    unsigned short* nxtb = kv[(s & 1) ^ 1];
    const int f0 = s * 32;
    if (s < 7) issue(vb, (s + 1) * 32, st);
    half2v acc[16];
#pragma unroll
    for (int a = 0; a < 16; ++a) acc[a] = half2v{(_Float16)0, (_Float16)0};
    __builtin_amdgcn_s_setprio(1);
#pragma unroll
    for (int i = 0; i < 7; ++i)
#pragma unroll
      for (int j = 0; j < 7; ++j) {
        const uint4* vp = (const uint4*)&curb[pbase + (i * 22 + j) * 40];
        uint4 v0 = vp[0], v1 = vp[1], v2 = vp[2], v3 = vp[3];
        const half2v p2 = h2cast(pw[i * 7 + j]);
        acc[0] += p2 * h2cast(v0.x);  acc[1] += p2 * h2cast(v0.y);
        acc[2] += p2 * h2cast(v0.z);  acc[3] += p2 * h2cast(v0.w);
        acc[4] += p2 * h2cast(v1.x);  acc[5] += p2 * h2cast(v1.y);
        acc[6] += p2 * h2cast(v1.z);  acc[7] += p2 * h2cast(v1.w);
        acc[8] += p2 * h2cast(v2.x);  acc[9] += p2 * h2cast(v2.y);
        acc[10] += p2 * h2cast(v2.z); acc[11] += p2 * h2cast(v2.w);
        acc[12] += p2 * h2cast(v3.x); acc[13] += p2 * h2cast(v3.y);
        acc[14] += p2 * h2cast(v3.z); acc[15] += p2 * h2cast(v3.w);
      }
    __builtin_amdgcn_s_setprio(0);
    if (s < 7) commit(nxtb, st);
#pragma unroll
    for (int fq = 0; fq < 8; ++fq) {
      float4 bv = *(const float4*)&bias[f0 + fq * 4];
      float4 o;
      o.x = (float)acc[fq * 2 + 0][0] + bv.x;
      o.y = (float)acc[fq * 2 + 0][1] + bv.y;
      o.z = (float)acc[fq * 2 + 1][0] + bv.z;
      o.w = (float)acc[fq * 2 + 1][1] + bv.w;
      *(float4*)&out[pix * 256 + f0 + fq * 4] = o;
    }
    if (s < 7) __syncthreads();
  }
}

extern "C" void kernel_launch(void* const* d_in, const int* in_sizes, int n_in,
                              void* d_out, int out_size, void* d_ws, size_t ws_size,
                              hipStream_t stream) {
  const float* x = (const float*)d_in[0];
  const float* Wq = (const float*)d_in[1];
  const float* Wk = (const float*)d_in[2];
  const float* Wv = (const float*)d_in[3];
  const float* relx = (const float*)d_in[4];
  const float* rely = (const float*)d_in[5];
  const float* bias = (const float*)d_in[6];
  float* out = (float*)d_out;

  // d_out doubles as scratch: xh (fp16 x) dead after qkv_gemm; qrel writes 32 B into each
  // pixel's out slot head, read by attn before that slot is overwritten.
  unsigned short* xh = (unsigned short*)d_out;
  unsigned short* qrl = (unsigned short*)d_out;
  // ws layout: Wb (fp16, 768*256 = 384 KB) | qkv (3 * 33554432 fp16 = 192 MB)
  unsigned short* Wb = (unsigned short*)d_ws;
  unsigned short* qkv = (unsigned short*)((char*)d_ws + 393216);

  xcvt<<<dim3(16384), dim3(256), 0, stream>>>(x, xh);
  wconv<<<dim3(768), dim3(256), 0, stream>>>(Wq, Wk, Wv, Wb);
  qkv_gemm<<<dim3(6144), dim3(256), 0, stream>>>(xh, Wb, qkv);
  qrel<<<dim3(512), dim3(256), 0, stream>>>(qkv, relx, rely, qrl);
  attn<<<dim3(512), dim3(256), 0, stream>>>(qkv, bias, qrl, out);
}

// Round 2
// 281.237 us; speedup vs baseline: 6.4734x; 6.4734x over previous
//
#include <hip/hip_runtime.h>
#include <hip/hip_fp16.h>
#include <stdint.h>

// Problem constants: B=8, H=W=128, C=F=256, K=7, PAD=3, rs=128
typedef _Float16 half8 __attribute__((ext_vector_type(8)));   // 8 fp16 = 4 VGPR (MFMA A/B frag)
typedef _Float16 half2v __attribute__((ext_vector_type(2)));  // packed fp16 pair
typedef __attribute__((ext_vector_type(4))) float f32x4;      // MFMA C/D frag

__device__ __forceinline__ unsigned short f2h(float f) {      // RNE fp32->fp16
  __half h = __float2half(f);
  unsigned short u; __builtin_memcpy(&u, &h, 2); return u;
}
__device__ __forceinline__ unsigned pk2h(float a, float b) {  // RTZ packed pair (staging only)
  auto v = __builtin_amdgcn_cvt_pkrtz(a, b);
  unsigned u; __builtin_memcpy(&u, &v, 4); return u;
}
__device__ __forceinline__ half2v h2cast(unsigned u) {
  half2v v; __builtin_memcpy(&v, &u, 4); return v;
}

#if __has_builtin(__builtin_amdgcn_fdot2)
__device__ __forceinline__ float dot2(half2v a, half2v b, float c) {
  return __builtin_amdgcn_fdot2(a, b, c, false);
}
#else
__device__ __forceinline__ float dot2(half2v a, half2v b, float c) {
  return c + (float)a[0] * (float)b[0] + (float)a[1] * (float)b[1];
}
#endif

// async global->LDS, 16B per lane; lds dest = wave-uniform base + lane*16
__device__ __forceinline__ void gl_lds16(const void* g, void* l) {
  __builtin_amdgcn_global_load_lds(
      (const __attribute__((address_space(1))) void*)g,
      (__attribute__((address_space(3))) void*)l, 16, 0, 0);
}

// ---------------- Kernel 0: x fp32 -> fp16 (into d_out scratch region) ----------------
__global__ __launch_bounds__(256) void xcvt(const float* __restrict__ x,
                                            unsigned short* __restrict__ xh) {
  const size_t i = ((size_t)blockIdx.x * 256 + threadIdx.x) * 8;
  float4 a = *(const float4*)&x[i];
  float4 b = *(const float4*)&x[i + 4];
  uint4 o;
  o.x = pk2h(a.x, a.y); o.y = pk2h(a.z, a.w);
  o.z = pk2h(b.x, b.y); o.w = pk2h(b.z, b.w);
  *(uint4*)&xh[i] = o;
}

// ---------------- Kernel 1: weight transpose + fp32->fp16 ----------------
__global__ __launch_bounds__(256) void wconv(const float* __restrict__ Wq,
                                             const float* __restrict__ Wk,
                                             const float* __restrict__ Wv,
                                             unsigned short* __restrict__ Wb) {
  const int e = blockIdx.x;
  const int w = e >> 8;
  const int n = e & 255;
  const float* W = (w == 0) ? Wq : ((w == 1) ? Wk : Wv);
  const int k = threadIdx.x;
  Wb[(size_t)e * 256 + k] = f2h(W[(size_t)k * 256 + n]);
}

// ---------------- Kernel 2: fused QKV GEMM (fp16 MFMA, global_load_lds staging) ----------
__global__ __launch_bounds__(256) void qkv_gemm(const unsigned short* __restrict__ xh,
                                                const unsigned short* __restrict__ Wb,
                                                unsigned short* __restrict__ qkv) {
  __shared__ unsigned char ldsb[32768];

  const int tid = threadIdx.x;
  const int l = tid & 63, l15 = l & 15, l4 = l >> 4;
  const int wv = tid >> 6, wr = wv >> 1, wc = wv & 1;

  // XCD-aware chunked swizzle: 6144 blocks, 8 XCDs, 768 per XCD (bijective).
  const int pid = blockIdx.x;
  const int cid = (pid & 7) * 768 + (pid >> 3);
  const int by = cid / 6;
  const int bx = cid - by * 6;
  const size_t row0 = (size_t)by * 128;
  const int n0 = bx * 128;

  const int rbase0 = wv * 32, rbase1 = wv * 32 + 16;
  const int rA0 = rbase0 + (l >> 2), rA1 = rbase1 + (l >> 2);
  const int q0 = (l & 3) ^ ((rA0 >> 1) & 3), q1 = (l & 3) ^ ((rA1 >> 1) & 3);
  const unsigned short* gA0 = xh + (row0 + rA0) * 256 + q0 * 8;
  const unsigned short* gA1 = xh + (row0 + rA1) * 256 + q1 * 8;
  const unsigned short* gB0 = Wb + (size_t)(n0 + rA0) * 256 + q0 * 8;
  const unsigned short* gB1 = Wb + (size_t)(n0 + rA1) * 256 + q1 * 8;

  f32x4 acc[4][4] = {};

  auto stage = [&](int s, int d) {
    gl_lds16(gA0 + s * 32, &ldsb[d * 8192 + rbase0 * 64]);
    gl_lds16(gA1 + s * 32, &ldsb[d * 8192 + rbase1 * 64]);
    gl_lds16(gB0 + s * 32, &ldsb[16384 + d * 8192 + rbase0 * 64]);
    gl_lds16(gB1 + s * 32, &ldsb[16384 + d * 8192 + rbase1 * 64]);
  };

  stage(0, 0);
  __syncthreads();

  for (int s = 0; s < 8; ++s) {
    const int d = s & 1;
    if (s < 7) stage(s + 1, d ^ 1);
    half8 af[4], bf[4];
#pragma unroll
    for (int m = 0; m < 4; ++m) {
      const int r = wr * 64 + m * 16 + l15;
      af[m] = *(const half8*)&ldsb[d * 8192 + r * 64 + ((l4 ^ ((r >> 1) & 3)) * 16)];
    }
#pragma unroll
    for (int n = 0; n < 4; ++n) {
      const int r = wc * 64 + n * 16 + l15;
      bf[n] = *(const half8*)&ldsb[16384 + d * 8192 + r * 64 + ((l4 ^ ((r >> 1) & 3)) * 16)];
    }
#pragma unroll
    for (int n = 0; n < 4; ++n)
#pragma unroll
      for (int m = 0; m < 4; ++m)
        acc[m][n] = __builtin_amdgcn_mfma_f32_16x16x32_f16(af[m], bf[n], acc[m][n], 0, 0, 0);
    __syncthreads();
  }

  // Epilogue: C/D mapping col=lane&15, row=(lane>>4)*4+reg (m89-verified)
#pragma unroll
  for (int m = 0; m < 4; ++m)
#pragma unroll
    for (int n = 0; n < 4; ++n) {
      const int ng = n0 + wc * 64 + n * 16 + l15;
      unsigned short* op = qkv + (size_t)(ng >> 8) * 33554432 + (ng & 255);
#pragma unroll
      for (int r = 0; r < 4; ++r) {
        const size_t grow = row0 + wr * 64 + m * 16 + l4 * 4 + r;
        op[grow * 256] = f2h(acc[m][n][r]);
      }
    }
}

// ---------------- Kernel 2b: per-pixel relative-position projections ----------------
__global__ __launch_bounds__(256) void qrel(const unsigned short* __restrict__ q,
                                            const float* __restrict__ relx,
                                            const float* __restrict__ rely,
                                            unsigned short* __restrict__ qr) {
  __shared__ unsigned wpk[896];  // [0..447] x-pairs, [448..895] y-pairs; wpk[c2*7+j]
  for (int i = threadIdx.x; i < 896; i += 256) {
    const int hf = (i >= 448) ? 1 : 0;
    const int r = i - hf * 448;
    const int c2 = r / 7, j = r - c2 * 7;
    const float* R = hf ? rely : relx;
    wpk[i] = pk2h(R[(2 * c2) * 7 + j], R[(2 * c2 + 1) * 7 + j]);
  }
  __syncthreads();
  const size_t pix = (size_t)blockIdx.x * 256 + threadIdx.x;
  const uint4* qp = (const uint4*)(q + pix * 256);  // 32 uint4 = 256 fp16 channels
  float ax[7] = {0, 0, 0, 0, 0, 0, 0}, ay[7] = {0, 0, 0, 0, 0, 0, 0};
#pragma unroll
  for (int g = 0; g < 32; ++g) {
    const uint4 u = qp[g];
    const int c2b = (g & 15) * 4;
    if (g < 16) {
#pragma unroll
      for (int j = 0; j < 7; ++j) {
        float s = ax[j];
        s = dot2(h2cast(u.x), h2cast(wpk[(c2b + 0) * 7 + j]), s);
        s = dot2(h2cast(u.y), h2cast(wpk[(c2b + 1) * 7 + j]), s);
        s = dot2(h2cast(u.z), h2cast(wpk[(c2b + 2) * 7 + j]), s);
        s = dot2(h2cast(u.w), h2cast(wpk[(c2b + 3) * 7 + j]), s);
        ax[j] = s;
      }
    } else {
#pragma unroll
      for (int j = 0; j < 7; ++j) {
        float s = ay[j];
        s = dot2(h2cast(u.x), h2cast(wpk[448 + (c2b + 0) * 7 + j]), s);
        s = dot2(h2cast(u.y), h2cast(wpk[448 + (c2b + 1) * 7 + j]), s);
        s = dot2(h2cast(u.z), h2cast(wpk[448 + (c2b + 2) * 7 + j]), s);
        s = dot2(h2cast(u.w), h2cast(wpk[448 + (c2b + 3) * 7 + j]), s);
        ay[j] = s;
      }
    }
  }
  uint4 o0, o1;
  o0.x = pk2h(ax[0], ax[1]); o0.y = pk2h(ax[2], ax[3]);
  o0.z = pk2h(ax[4], ax[5]); o0.w = pk2h(ax[6], ay[0]);
  o1.x = pk2h(ay[1], ay[2]); o1.y = pk2h(ay[3], ay[4]);
  o1.z = pk2h(ay[5], ay[6]); o1.w = 0;
  uint4* dst = (uint4*)(qr + pix * 512);
  dst[0] = o0; dst[1] = o1;
}

// ---------------- Kernel 3: fused windowed attention ----------------
// v3: async double-buffered staging via global_load_lds (ZERO register cost — v2's
// register staging spilled: VGPR 256, 5 GB scratch traffic, 10x regression).
// Geometry reverted to the r6-proven 8x32 tile (halo 14x38 = 532 px, grid 512).
// LDS is PLANE-MAJOR: kv[2 buf][4 planes][532 px * 16 B]. gl_lds dest = wave-uniform
// base + lane*16 -> lane==pixel linear per plane; reads are 4x ds_read_b128 at 16 B
// lane stride (canonical conflict-free). OOB halo slots are a static set: zeroed once
// for both buffers; gl_lds exec-masking never writes them.
// Pipeline per chunk: issue next chunk's gl_lds -> 49-tap compute -> ONE barrier
// (its implicit vmcnt(0) lands after ~2000 cyc of compute). 17 barriers vs 33.
__global__ __launch_bounds__(256) void attn(const unsigned short* __restrict__ qkv,
                                            const float* __restrict__ bias,
                                            const unsigned short* __restrict__ qrelb,
                                            float* __restrict__ out) {
  __shared__ unsigned short kv[2][4][4256];  // 2 x 4 x 8512 B = 68096 B

  const int tid = threadIdx.x;
  const int col = tid & 31, row = tid >> 5;

  const int pid = blockIdx.x;
  const int cid = (pid & 7) * 64 + (pid >> 3);   // XCD-chunked (512 = 8*64, bijective)
  const int ht = cid & 15, wt = (cid >> 4) & 3, b = cid >> 6;

  const int h = ht * 8 + row, w = wt * 32 + col;
  const size_t pix = (size_t)((b * 128 + h) * 128 + w);
  const int pbase = row * 38 + col;              // this thread's halo-pixel index

  const unsigned short* qb = qkv;
  const unsigned short* kb = qkv + 33554432;
  const unsigned short* vb = qkv + 67108864;

  // staging geometry: thread covers halo px tid, tid+256, tid+512 (532 total)
  const int pr0 = tid / 38, pc0 = tid - pr0 * 38;
  const int gh0 = ht * 8 + pr0 - 3, gw0 = wt * 32 + pc0 - 3;
  const bool ok0 = ((unsigned)gh0 < 128u) && ((unsigned)gw0 < 128u);
  const long long go0 = ((long long)((b * 128 + gh0) * 128 + gw0)) * 256;  // shorts

  const int p1 = tid + 256;
  const int pr1 = p1 / 38, pc1 = p1 - pr1 * 38;
  const int gh1 = ht * 8 + pr1 - 3, gw1 = wt * 32 + pc1 - 3;
  const bool ok1 = ((unsigned)gh1 < 128u) && ((unsigned)gw1 < 128u);
  const long long go1 = ((long long)((b * 128 + gh1) * 128 + gw1)) * 256;

  const int p2 = tid + 512;
  const int pr2 = p2 / 38, pc2 = p2 - pr2 * 38;
  const int gh2 = ht * 8 + pr2 - 3, gw2 = wt * 32 + pc2 - 3;
  const bool ok2 = (p2 < 532) && ((unsigned)gh2 < 128u) && ((unsigned)gw2 < 128u);
  const long long go2 = ((long long)((b * 128 + gh2) * 128 + gw2)) * 256;

  const int wb8 = (tid >> 6) * 512;  // wave's pixel-group base * 8 shorts

  // issue async stage of chunk c of `base` into buffer d (no registers, no waits)
  auto stage = [&](const unsigned short* base, int c, int d) {
#pragma unroll
    for (int g = 0; g < 4; ++g) {
      if (ok0) gl_lds16(base + go0 + c * 32 + g * 8, &kv[d][g][wb8]);
      if (ok1) gl_lds16(base + go1 + c * 32 + g * 8, &kv[d][g][2048 + wb8]);
      if (ok2) gl_lds16(base + go2 + c * 32 + g * 8, &kv[d][g][4096]);
    }
  };

  // zero the static OOB halo slots once, for both buffers (gl_lds never writes them)
  {
    const uint4 z = make_uint4(0u, 0u, 0u, 0u);
    for (int p = tid; p < 532; p += 256) {
      const int pr = p / 38, pc = p - pr * 38;
      const int gh = ht * 8 + pr - 3, gw = wt * 32 + pc - 3;
      if (!((unsigned)gh < 128u && (unsigned)gw < 128u)) {
#pragma unroll
        for (int d = 0; d < 2; ++d)
#pragma unroll
          for (int g = 0; g < 4; ++g)
            *(uint4*)&kv[d][g][p * 8] = z;
      }
    }
  }

  // qrel: 14 fp16 at this pixel's out-slot head (written by qrel; we overwrite later)
  float qx[7], qy[7];
  {
    const uint4* rp = (const uint4*)(qrelb + pix * 512);
    uint4 r0 = rp[0], r1 = rp[1];
    half2v a0 = h2cast(r0.x), a1 = h2cast(r0.y), a2 = h2cast(r0.z), a3 = h2cast(r0.w);
    half2v b0 = h2cast(r1.x), b1 = h2cast(r1.y), b2 = h2cast(r1.z);
    qx[0] = a0[0]; qx[1] = a0[1]; qx[2] = a1[0]; qx[3] = a1[1];
    qx[4] = a2[0]; qx[5] = a2[1]; qx[6] = a3[0];
    qy[0] = a3[1]; qy[1] = b0[0]; qy[2] = b0[1]; qy[3] = b1[0];
    qy[4] = b1[1]; qy[5] = b2[0]; qy[6] = b2[1];
  }

  stage(kb, 0, 0);
  __syncthreads();   // implicit vmcnt(0): chunk-0 K staged + OOB zeros visible

  float sc[49];
#pragma unroll
  for (int t = 0; t < 49; ++t) sc[t] = 0.0f;

  // ---- Phase A: scores (double-buffered, one barrier per chunk) ----
  for (int s = 0; s < 8; ++s) {
    const int d = s & 1;
    // issue next stage NOW; its latency hides under the 49-tap compute below
    stage(s < 7 ? kb : vb, s < 7 ? s + 1 : 0, d ^ 1);
    const uint4* qsrc = (const uint4*)(qb + pix * 256 + s * 32);
    uint4 u0 = qsrc[0], u1 = qsrc[1], u2 = qsrc[2], u3 = qsrc[3];
    half2v qh[16];
    qh[0] = h2cast(u0.x); qh[1] = h2cast(u0.y); qh[2] = h2cast(u0.z); qh[3] = h2cast(u0.w);
    qh[4] = h2cast(u1.x); qh[5] = h2cast(u1.y); qh[6] = h2cast(u1.z); qh[7] = h2cast(u1.w);
    qh[8] = h2cast(u2.x); qh[9] = h2cast(u2.y); qh[10] = h2cast(u2.z); qh[11] = h2cast(u2.w);
    qh[12] = h2cast(u3.x); qh[13] = h2cast(u3.y); qh[14] = h2cast(u3.z); qh[15] = h2cast(u3.w);
    __builtin_amdgcn_s_setprio(1);
#pragma unroll
    for (int i = 0; i < 7; ++i)
#pragma unroll
      for (int j = 0; j < 7; ++j) {
        const int q8 = (pbase + i * 38 + j) * 8;
        uint4 k0 = *(const uint4*)&kv[d][0][q8];
        uint4 k1 = *(const uint4*)&kv[d][1][q8];
        uint4 k2 = *(const uint4*)&kv[d][2][q8];
        uint4 k3 = *(const uint4*)&kv[d][3][q8];
        float s2 = sc[i * 7 + j];
        s2 = dot2(h2cast(k0.x), qh[0], s2);  s2 = dot2(h2cast(k0.y), qh[1], s2);
        s2 = dot2(h2cast(k0.z), qh[2], s2);  s2 = dot2(h2cast(k0.w), qh[3], s2);
        s2 = dot2(h2cast(k1.x), qh[4], s2);  s2 = dot2(h2cast(k1.y), qh[5], s2);
        s2 = dot2(h2cast(k1.z), qh[6], s2);  s2 = dot2(h2cast(k1.w), qh[7], s2);
        s2 = dot2(h2cast(k2.x), qh[8], s2);  s2 = dot2(h2cast(k2.y), qh[9], s2);
        s2 = dot2(h2cast(k2.z), qh[10], s2); s2 = dot2(h2cast(k2.w), qh[11], s2);
        s2 = dot2(h2cast(k3.x), qh[12], s2); s2 = dot2(h2cast(k3.y), qh[13], s2);
        s2 = dot2(h2cast(k3.z), qh[14], s2); s2 = dot2(h2cast(k3.w), qh[15], s2);
        sc[i * 7 + j] = s2;
      }
    __builtin_amdgcn_s_setprio(0);
    __syncthreads();   // staged next chunk visible; current buffer free for reuse
  }

  // ---- softmax over 49 (fp32, per thread); V chunk 0 already staged in buf 0 ----
#pragma unroll
  for (int i = 0; i < 7; ++i)
#pragma unroll
    for (int j = 0; j < 7; ++j) sc[i * 7 + j] += qx[j] + qy[i];
  float mx = sc[0];
#pragma unroll
  for (int t = 1; t < 49; ++t) mx = fmaxf(mx, sc[t]);
  float sum = 0.0f;
#pragma unroll
  for (int t = 0; t < 49; ++t) {
    float e = __expf(sc[t] - mx);
    sc[t] = e;
    sum += e;
  }
  const float invs = 1.0f / sum;
  unsigned pw[49];
#pragma unroll
  for (int t = 0; t < 49; ++t) {
    const unsigned short ph = f2h(sc[t] * invs);
    pw[t] = (unsigned)ph | ((unsigned)ph << 16);
  }

  // ---- Phase B: out = sum p*v + bias (same pipeline; parity continues at buf 0) ----
  for (int s = 0; s < 8; ++s) {
    const int d = s & 1;
    const int f0 = s * 32;
    if (s < 7) stage(vb, s + 1, d ^ 1);
    half2v acc[16];
#pragma unroll
    for (int a = 0; a < 16; ++a) acc[a] = half2v{(_Float16)0, (_Float16)0};
    __builtin_amdgcn_s_setprio(1);
#pragma unroll
    for (int i = 0; i < 7; ++i)
#pragma unroll
      for (int j = 0; j < 7; ++j) {
        const int q8 = (pbase + i * 38 + j) * 8;
        uint4 v0 = *(const uint4*)&kv[d][0][q8];
        uint4 v1 = *(const uint4*)&kv[d][1][q8];
        uint4 v2 = *(const uint4*)&kv[d][2][q8];
        uint4 v3 = *(const uint4*)&kv[d][3][q8];
        const half2v p2h = h2cast(pw[i * 7 + j]);
        acc[0] += p2h * h2cast(v0.x);  acc[1] += p2h * h2cast(v0.y);
        acc[2] += p2h * h2cast(v0.z);  acc[3] += p2h * h2cast(v0.w);
        acc[4] += p2h * h2cast(v1.x);  acc[5] += p2h * h2cast(v1.y);
        acc[6] += p2h * h2cast(v1.z);  acc[7] += p2h * h2cast(v1.w);
        acc[8] += p2h * h2cast(v2.x);  acc[9] += p2h * h2cast(v2.y);
        acc[10] += p2h * h2cast(v2.z); acc[11] += p2h * h2cast(v2.w);
        acc[12] += p2h * h2cast(v3.x); acc[13] += p2h * h2cast(v3.y);
        acc[14] += p2h * h2cast(v3.z); acc[15] += p2h * h2cast(v3.w);
      }
    __builtin_amdgcn_s_setprio(0);
#pragma unroll
    for (int fq = 0; fq < 8; ++fq) {
      float4 bv = *(const float4*)&bias[f0 + fq * 4];
      float4 o;
      o.x = (float)acc[fq * 2 + 0][0] + bv.x;
      o.y = (float)acc[fq * 2 + 0][1] + bv.y;
      o.z = (float)acc[fq * 2 + 1][0] + bv.z;
      o.w = (float)acc[fq * 2 + 1][1] + bv.w;
      *(float4*)&out[pix * 256 + f0 + fq * 4] = o;
    }
    if (s < 7) __syncthreads();
  }
}

extern "C" void kernel_launch(void* const* d_in, const int* in_sizes, int n_in,
                              void* d_out, int out_size, void* d_ws, size_t ws_size,
                              hipStream_t stream) {
  const float* x = (const float*)d_in[0];
  const float* Wq = (const float*)d_in[1];
  const float* Wk = (const float*)d_in[2];
  const float* Wv = (const float*)d_in[3];
  const float* relx = (const float*)d_in[4];
  const float* rely = (const float*)d_in[5];
  const float* bias = (const float*)d_in[6];
  float* out = (float*)d_out;

  // d_out doubles as scratch: xh (fp16 x) dead after qkv_gemm; qrel writes 32 B into each
  // pixel's out slot head, read by attn before that slot is overwritten.
  unsigned short* xh = (unsigned short*)d_out;
  unsigned short* qrl = (unsigned short*)d_out;
  // ws layout: Wb (fp16, 768*256 = 384 KB) | qkv (3 * 33554432 fp16 = 192 MB)
  unsigned short* Wb = (unsigned short*)d_ws;
  unsigned short* qkv = (unsigned short*)((char*)d_ws + 393216);

  xcvt<<<dim3(16384), dim3(256), 0, stream>>>(x, xh);
  wconv<<<dim3(768), dim3(256), 0, stream>>>(Wq, Wk, Wv, Wb);
  qkv_gemm<<<dim3(6144), dim3(256), 0, stream>>>(xh, Wb, qkv);
  qrel<<<dim3(512), dim3(256), 0, stream>>>(qkv, relx, rely, qrl);
  attn<<<dim3(512), dim3(256), 0, stream>>>(qkv, bias, qrl, out);
}